// Round 5
// baseline (667.150 us; speedup 1.0000x reference)
//
#include <hip/hip_runtime.h>
#include <hip/hip_cooperative_groups.h>

namespace cg = cooperative_groups;

// HIGNN, round 19: single cooperative kernel = setup + p1 + p2 with
// grid.sync() between phases.
//  - R18 lesson: global fp32 atomics = memory-side RMW (309MB HBM writes) ->
//    bucket/records pipeline restored, and p2's final combine is DIRECT WRITE
//    (partial tiles + sum phase), zero global atomics.
//  - Phase1 MLP identical to R17's 126us p1 (LDS 64B-row fp16 weights, KPT=4,
//    deferred gcount publish), grid-strided over 1024-edge tiles.
//  - One dispatch => dur_us - kernel_dur isolates the harness floor.
//  - Cooperative launch failure -> known-correct atomic fallback.

constexpr int HIDDEN = 64;
constexpr int NB_MAX = 256;      // histogram bins (>= nbuckets)
constexpr int NPB_SHIFT = 9;     // 512 nodes per bucket
constexpr int NPB = 1 << NPB_SHIFT;
constexpr int TILE_F = NPB * 3;  // floats per bucket tile (1536)
constexpr int NET_SLOT = 1040;   // dwords per packed-net slot
constexpr int PSPLIT = 4;        // phase-2 parts per bucket
constexpr int BLK = 256;
constexpr int KPT = 4;

typedef _Float16 h2_t __attribute__((ext_vector_type(2)));

__device__ __forceinline__ unsigned packh2(float a, float b) {
    auto h = __builtin_amdgcn_cvt_pkrtz(a, b);   // __fp16 ext_vector(2)
    return __builtin_bit_cast(unsigned, h);
}
__device__ __forceinline__ float fdot2u(unsigned a, unsigned b, float c) {
    h2_t ha = __builtin_bit_cast(h2_t, a);
    h2_t hb = __builtin_bit_cast(h2_t, b);
#if __has_builtin(__builtin_amdgcn_fdot2)
    return __builtin_amdgcn_fdot2(ha, hb, c, false);
#else
    return fmaf((float)ha.x, (float)hb.x, fmaf((float)ha.y, (float)hb.y, c));
#endif
}

// Packed net slot layout (dword indices within NET_SLOT):
// din3 nets (2body, self): row per hh2 at h2*16 (64B aligned):
//   [0]=wA  [1]=wB  [2]=b1A f32  [3]=b1B f32  [4]=w1cA f32  [5]=w1cB f32
//   [6..14]=w2p[0..8] packed     [15]=pad
// din6 net (3body): row per hh2 at h2*32 (128B aligned):
//   [0..2]=wA0..2  [3..5]=wB0..2  [6]=b1A  [7]=b1B  [8..16]=w2p  [17..31]=pad
// all nets: [1024..1032] = b2[0..8] f32

struct FusedArgs {
    const float* x; int n_nodes;
    const int* e0; long long E0; const float* at0;
    const int* e1; long long E1; const float* at1;
    const int* e2; long long E2; const float* at2;
    int g0, g1, T, nbuckets, cap;
    const float *W1_2b, *b1_2b, *W2_2b, *b2_2b;
    const float *W1_s,  *b1_s,  *W2_s,  *b2_s;
    const float *W1_3b, *b1_3b, *W2_3b, *b2_3b;
    unsigned* nets; float4* x4; int* gcount;
    float4* records; float* partials; float* out;
};

__global__ __launch_bounds__(256, 4) void fused_kernel(FusedArgs A)
{
    static_assert(NB_MAX == BLK, "one reserve bin per thread");
    __shared__ union U {
        struct {
            __align__(16) unsigned net[1033];
            int hist[NB_MAX]; int base[NB_MAX]; int rank[NB_MAX];
        } p1;
        __align__(16) float acc[TILE_F];
    } sh;

    const int tid = threadIdx.x;
    const int bid = blockIdx.x;
    const int G = gridDim.x;
    cg::grid_group grid = cg::this_grid();

    // ================= Phase 0: pack nets, zero gcount, build x4 ==========
    if (bid < 3) {
        const float *W1, *b1, *W2, *b2; int din;
        if (bid == 0) { W1 = A.W1_2b; b1 = A.b1_2b; W2 = A.W2_2b; b2 = A.b2_2b; din = 3; }
        else if (bid == 1) { W1 = A.W1_s; b1 = A.b1_s; W2 = A.W2_s; b2 = A.b2_s; din = 3; }
        else { W1 = A.W1_3b; b1 = A.b1_3b; W2 = A.W2_3b; b2 = A.b2_3b; din = 6; }
        unsigned* slot = A.nets + bid * NET_SLOT;
        float* slotf = (float*)slot;
        if (tid < 32) {
            const int h2 = tid, hA = 2 * h2, hB = 2 * h2 + 1;
            if (din == 3) {
                unsigned* row = slot + h2 * 16;
                float* rowf = (float*)row;
                row[0] = packh2(W1[0 * HIDDEN + hA], W1[1 * HIDDEN + hA]);
                row[1] = packh2(W1[0 * HIDDEN + hB], W1[1 * HIDDEN + hB]);
                rowf[2] = b1[hA]; rowf[3] = b1[hB];
                rowf[4] = W1[2 * HIDDEN + hA]; rowf[5] = W1[2 * HIDDEN + hB];
                #pragma unroll
                for (int i = 0; i < 9; ++i)
                    row[6 + i] = packh2(W2[hA * 9 + i], W2[hB * 9 + i]);
                row[15] = 0;
            } else {
                unsigned* row = slot + h2 * 32;
                float* rowf = (float*)row;
                #pragma unroll
                for (int r = 0; r < 3; ++r) {
                    row[r]     = packh2(W1[(2 * r) * HIDDEN + hA], W1[(2 * r + 1) * HIDDEN + hA]);
                    row[3 + r] = packh2(W1[(2 * r) * HIDDEN + hB], W1[(2 * r + 1) * HIDDEN + hB]);
                }
                rowf[6] = b1[hA]; rowf[7] = b1[hB];
                #pragma unroll
                for (int i = 0; i < 9; ++i)
                    row[8 + i] = packh2(W2[hA * 9 + i], W2[hB * 9 + i]);
                #pragma unroll
                for (int i = 17; i < 20; ++i) row[i] = 0;
            }
        }
        if (tid >= 32 && tid < 41) slotf[1024 + (tid - 32)] = b2[tid - 32];
    }
    if (bid == 3) A.gcount[tid] = 0;   // 256 threads zero all NB_MAX bins
    for (int i = bid * BLK + tid; i < A.n_nodes; i += G * BLK) {
        A.x4[i] = make_float4(A.x[3 * i], A.x[3 * i + 1], A.x[3 * i + 2], 0.0f);
    }

    __threadfence();
    grid.sync();

    // ================= Phase 1: MLP + bucket append (grid-stride tiles) ===
    int cur_set = -1;
    for (int t = bid; t < A.T; t += G) {
        const int* edges; long long E; const float* attr; int din3, set, t2;
        if (t < A.g0)            { set = 0; edges = A.e0; E = A.E0; attr = A.at0; din3 = 1; t2 = t; }
        else if (t < A.g0 + A.g1){ set = 1; edges = A.e1; E = A.E1; attr = A.at1; din3 = 1; t2 = t - A.g0; }
        else                     { set = 2; edges = A.e2; E = A.E2; attr = A.at2; din3 = 0; t2 = t - A.g0 - A.g1; }

        __syncthreads();   // prior tile done with s_net/base/rank
        for (int i = tid; i < NB_MAX; i += BLK) { sh.p1.hist[i] = 0; sh.p1.rank[i] = 0; }
        if (set != cur_set) {   // block-uniform
            const unsigned* wp = A.nets + set * NET_SLOT;
            for (int i = tid; i < 1033; i += BLK) sh.p1.net[i] = wp[i];
            cur_set = set;
        }
        __syncthreads();

        const unsigned* w = sh.p1.net;
        const float* wf = (const float*)sh.p1.net;
        float b2r[9];
        #pragma unroll
        for (int i = 0; i < 9; ++i) b2r[i] = wf[1024 + i];

        const long long lo = (long long)t2 << 10;
        const long long hi = (lo + 1024 < E) ? lo + 1024 : E;
        const bool e_al = ((E & 3) == 0);
        const long long dstrow = din3 ? E : 2 * E;
        const long long be = lo + (long long)tid * KPT;   // 4-aligned

        // --- histogram (single shot: BLK*KPT == tile span) ---
        if (be < hi) {
            if (e_al && be + KPT <= hi) {
                int4 r = *(const int4*)(edges + dstrow + be);
                atomicAdd(&sh.p1.hist[r.x >> NPB_SHIFT], 1);
                atomicAdd(&sh.p1.hist[r.y >> NPB_SHIFT], 1);
                atomicAdd(&sh.p1.hist[r.z >> NPB_SHIFT], 1);
                atomicAdd(&sh.p1.hist[r.w >> NPB_SHIFT], 1);
            } else {
                #pragma unroll
                for (int u = 0; u < KPT; ++u) {
                    long long e = be + u;
                    if (e < hi)
                        atomicAdd(&sh.p1.hist[edges[dstrow + e] >> NPB_SHIFT], 1);
                }
            }
        }
        __syncthreads();

        // reserve (issued now, published after MLP -> hides atomic latency)
        int my_base = 0;
        { int h = sh.p1.hist[tid]; if (h > 0) my_base = atomicAdd(&A.gcount[tid], h); }

        // --- loads ---
        unsigned dp[KPT][3];
        float    d2s[KPT];
        float    a[KPT][3];
        int      dst[KPT];
        bool     valid[KPT];
        int      i0[KPT], i1[KPT], i2[KPT];

        const bool full = e_al && (be + KPT <= hi);
        if (full) {
            int4 r0 = *(const int4*)(edges + be);
            int4 r1 = *(const int4*)(edges + E + be);
            i0[0] = r0.x; i0[1] = r0.y; i0[2] = r0.z; i0[3] = r0.w;
            i1[0] = r1.x; i1[1] = r1.y; i1[2] = r1.z; i1[3] = r1.w;
            if (!din3) {
                int4 r2 = *(const int4*)(edges + 2 * E + be);
                i2[0] = r2.x; i2[1] = r2.y; i2[2] = r2.z; i2[3] = r2.w;
            }
            float4 a0 = *(const float4*)(attr + 3 * be);
            float4 a1 = *(const float4*)(attr + 3 * be + 4);
            float4 a2 = *(const float4*)(attr + 3 * be + 8);
            a[0][0] = a0.x; a[0][1] = a0.y; a[0][2] = a0.z;
            a[1][0] = a0.w; a[1][1] = a1.x; a[1][2] = a1.y;
            a[2][0] = a1.z; a[2][1] = a1.w; a[2][2] = a2.x;
            a[3][0] = a2.y; a[3][1] = a2.z; a[3][2] = a2.w;
            #pragma unroll
            for (int u = 0; u < KPT; ++u) valid[u] = true;
        } else {
            #pragma unroll
            for (int u = 0; u < KPT; ++u) {
                long long e = be + u;
                valid[u] = (e < hi);
                long long ee = valid[u] ? e : lo;
                i0[u] = edges[ee];
                i1[u] = edges[E + ee];
                if (!din3) i2[u] = edges[2 * E + ee];
                #pragma unroll
                for (int c = 0; c < 3; ++c) a[u][c] = attr[3 * ee + c];
            }
        }

        // compute UNGUARDED (garbage on clamped lanes, append guarded)
        #pragma unroll
        for (int u = 0; u < KPT; ++u) {
            if (din3) {
                dst[u] = i1[u];
                float4 xs = A.x4[i0[u]];
                float4 xt = A.x4[i1[u]];
                dp[u][0] = packh2(xs.x - xt.x, xs.y - xt.y);
                d2s[u]   = xs.z - xt.z;
                dp[u][1] = 0; dp[u][2] = 0;
            } else {
                dst[u] = i2[u];
                float4 xj = A.x4[i0[u]];
                float4 xk = A.x4[i1[u]];
                float4 xi = A.x4[i2[u]];
                dp[u][0] = packh2(xk.x - xj.x, xk.y - xj.y);
                dp[u][1] = packh2(xk.z - xj.z, xi.x - xk.x);
                dp[u][2] = packh2(xi.y - xk.y, xi.z - xk.z);
                d2s[u] = 0.f;
            }
        }

        float acc[KPT][9];
        #pragma unroll
        for (int u = 0; u < KPT; ++u)
            #pragma unroll
            for (int i = 0; i < 9; ++i) acc[u][i] = b2r[i];

        if (din3) {
            #pragma unroll 2
            for (int hh2 = 0; hh2 < HIDDEN / 2; ++hh2) {
                const uint4* rq = (const uint4*)(w + (hh2 << 4));
                const uint4 q0 = rq[0], q1 = rq[1], q2 = rq[2], q3 = rq[3];
                const unsigned wA = q0.x;
                const unsigned wB = q0.y;
                const float bbA = __uint_as_float(q0.z);
                const float bbB = __uint_as_float(q0.w);
                const float wcA = __uint_as_float(q1.x);
                const float wcB = __uint_as_float(q1.y);
                const unsigned w2p[9] = {q1.z, q1.w, q2.x, q2.y, q2.z,
                                         q2.w, q3.x, q3.y, q3.z};
                #pragma unroll
                for (int u = 0; u < KPT; ++u) {
                    float preA = fmaf(d2s[u], wcA, fdot2u(dp[u][0], wA, bbA));
                    float preB = fmaf(d2s[u], wcB, fdot2u(dp[u][0], wB, bbB));
                    unsigned h2 = packh2(fmaxf(preA, 0.f), fmaxf(preB, 0.f));
                    #pragma unroll
                    for (int i = 0; i < 9; ++i)
                        acc[u][i] = fdot2u(h2, w2p[i], acc[u][i]);
                }
            }
        } else {
            #pragma unroll 2
            for (int hh2 = 0; hh2 < HIDDEN / 2; ++hh2) {
                const uint4* rq = (const uint4*)(w + (hh2 << 5));
                const uint4 q0 = rq[0], q1 = rq[1], q2 = rq[2], q3 = rq[3];
                const unsigned q4x = w[(hh2 << 5) + 16];
                const unsigned wA0 = q0.x, wA1 = q0.y, wA2 = q0.z;
                const unsigned wB0 = q0.w, wB1 = q1.x, wB2 = q1.y;
                const float bbA = __uint_as_float(q1.z);
                const float bbB = __uint_as_float(q1.w);
                const unsigned w2p[9] = {q2.x, q2.y, q2.z, q2.w, q3.x,
                                         q3.y, q3.z, q3.w, q4x};
                #pragma unroll
                for (int u = 0; u < KPT; ++u) {
                    float preA = fdot2u(dp[u][2], wA2,
                                 fdot2u(dp[u][1], wA1,
                                 fdot2u(dp[u][0], wA0, bbA)));
                    float preB = fdot2u(dp[u][2], wB2,
                                 fdot2u(dp[u][1], wB1,
                                 fdot2u(dp[u][0], wB0, bbB)));
                    unsigned h2 = packh2(fmaxf(preA, 0.f), fmaxf(preB, 0.f));
                    #pragma unroll
                    for (int i = 0; i < 9; ++i)
                        acc[u][i] = fdot2u(h2, w2p[i], acc[u][i]);
                }
            }
        }

        // publish reserve bases, then append
        sh.p1.base[tid] = my_base;
        __syncthreads();

        #pragma unroll
        for (int u = 0; u < KPT; ++u) {
            if (!valid[u]) continue;
            float y0 = fmaf(acc[u][0], a[u][0], fmaf(acc[u][1], a[u][1], acc[u][2] * a[u][2]));
            float y1 = fmaf(acc[u][3], a[u][0], fmaf(acc[u][4], a[u][1], acc[u][5] * a[u][2]));
            float y2 = fmaf(acc[u][6], a[u][0], fmaf(acc[u][7], a[u][1], acc[u][8] * a[u][2]));
            int b = dst[u] >> NPB_SHIFT;
            int r = atomicAdd(&sh.p1.rank[b], 1);
            int slot = sh.p1.base[b] + r;
            if (slot < A.cap)
                A.records[(size_t)b * A.cap + slot] =
                    make_float4(y0, y1, y2, __int_as_float(dst[u]));
        }
    }

    __threadfence();
    grid.sync();

    // ================= Phase 2a: per-part LDS reduce -> partial tiles =====
    const int nparts = A.nbuckets * PSPLIT;
    for (int part = bid; part < nparts; part += G) {
        const int b = part >> 2;     // PSPLIT == 4
        const int p = part & 3;
        __syncthreads();             // prior part done reading sh.acc
        for (int i = tid; i < TILE_F; i += BLK) sh.acc[i] = 0.0f;
        __syncthreads();
        int cnt = A.gcount[b];
        if (cnt > A.cap) cnt = A.cap;
        const float4* rb = A.records + (size_t)b * A.cap;
        for (int i = p * BLK + tid; i < cnt; i += PSPLIT * BLK) {
            float4 r = rb[i];
            int loc = __float_as_int(r.w) - (b << NPB_SHIFT);
            atomicAdd(&sh.acc[loc * 3 + 0], r.x);
            atomicAdd(&sh.acc[loc * 3 + 1], r.y);
            atomicAdd(&sh.acc[loc * 3 + 2], r.z);
        }
        __syncthreads();
        float4* pp = (float4*)(A.partials + (size_t)part * TILE_F);
        const float4* sa = (const float4*)sh.acc;
        for (int j = tid; j < TILE_F / 4; j += BLK) pp[j] = sa[j];
    }

    __threadfence();
    grid.sync();

    // ================= Phase 2b: sum PSPLIT partials -> out (direct) ======
    const int total = A.n_nodes * 3;
    for (int i = bid * BLK + tid; i < total; i += G * BLK) {
        int b = i / TILE_F;
        int off = i - b * TILE_F;
        const float* pb = A.partials + (size_t)(b * PSPLIT) * TILE_F + off;
        A.out[i] = (pb[0] + pb[TILE_F]) + (pb[2 * TILE_F] + pb[3 * TILE_F]);
    }
}

// ---------------- Fallback: direct device atomics, fp32 ----------------
template <int DIN, int KPTF>
__global__ __launch_bounds__(256) void edge_mlp_atomic(
    const float* __restrict__ x,
    const int* __restrict__ edges, long long E,
    const float* __restrict__ attr,
    const float* __restrict__ W1, const float* __restrict__ b1,
    const float* __restrict__ W2, const float* __restrict__ b2,
    float* __restrict__ out)
{
    const int tid = threadIdx.x;
    const long long base = (long long)blockIdx.x * (blockDim.x * KPTF) + tid;
    float d[KPTF][DIN]; float a[KPTF][3]; int dst[KPTF]; bool valid[KPTF];
    #pragma unroll
    for (int u = 0; u < KPTF; ++u) {
        long long e = base + (long long)u * blockDim.x;
        valid[u] = (e < E);
        long long ee = valid[u] ? e : 0;
        if constexpr (DIN == 3) {
            int s = edges[ee]; int t = edges[E + ee]; dst[u] = t;
            #pragma unroll
            for (int c = 0; c < 3; ++c)
                d[u][c] = x[3 * (long long)s + c] - x[3 * (long long)t + c];
        } else {
            int j = edges[ee]; int k = edges[E + ee]; int i = edges[2 * E + ee];
            dst[u] = i;
            #pragma unroll
            for (int c = 0; c < 3; ++c) {
                float xj = x[3 * (long long)j + c];
                float xk = x[3 * (long long)k + c];
                float xi = x[3 * (long long)i + c];
                d[u][c] = xk - xj; d[u][3 + c] = xi - xk;
            }
        }
        #pragma unroll
        for (int c = 0; c < 3; ++c) a[u][c] = attr[3 * ee + c];
    }
    float acc[KPTF][9];
    #pragma unroll
    for (int u = 0; u < KPTF; ++u)
        #pragma unroll
        for (int i = 0; i < 9; ++i) acc[u][i] = b2[i];
    #pragma unroll 4
    for (int hh = 0; hh < HIDDEN; ++hh) {
        const float bb = b1[hh];
        float w1r[DIN];
        #pragma unroll
        for (int r = 0; r < DIN; ++r) w1r[r] = W1[r * HIDDEN + hh];
        float w2r[9];
        #pragma unroll
        for (int i = 0; i < 9; ++i) w2r[i] = W2[hh * 9 + i];
        #pragma unroll
        for (int u = 0; u < KPTF; ++u) {
            float pre = bb;
            #pragma unroll
            for (int r = 0; r < DIN; ++r) pre = fmaf(d[u][r], w1r[r], pre);
            const float h = fmaxf(pre, 0.0f);
            #pragma unroll
            for (int i = 0; i < 9; ++i) acc[u][i] = fmaf(h, w2r[i], acc[u][i]);
        }
    }
    #pragma unroll
    for (int u = 0; u < KPTF; ++u) {
        if (!valid[u]) continue;
        float* o = out + 3 * (long long)dst[u];
        #pragma unroll
        for (int i = 0; i < 3; ++i) {
            float y = fmaf(acc[u][3 * i + 0], a[u][0],
                      fmaf(acc[u][3 * i + 1], a[u][1],
                           acc[u][3 * i + 2] * a[u][2]));
            atomicAdd(&o[i], y);
        }
    }
}

static void launch_fallback(const float* x,
                            const int* e2, long long E2, const float* a2,
                            const int* e3, long long E3, const float* a3,
                            const int* es, long long ES, const float* as,
                            const float* W1_2b, const float* b1_2b,
                            const float* W2_2b, const float* b2_2b,
                            const float* W1_3b, const float* b1_3b,
                            const float* W2_3b, const float* b2_3b,
                            const float* W1_s, const float* b1_s,
                            const float* W2_s, const float* b2_s,
                            float* out, int out_size, hipStream_t stream)
{
    hipMemsetAsync(out, 0, (size_t)out_size * sizeof(float), stream);
    constexpr int FB_BLK = 256, FB_KPT = 4;
    const long long per_blk = (long long)FB_BLK * FB_KPT;
    int a2g = (int)((E2 + per_blk - 1) / per_blk);
    int a3g = (int)((E3 + per_blk - 1) / per_blk);
    int asg = (int)((ES + per_blk - 1) / per_blk);
    if (a2g > 0)
        edge_mlp_atomic<3, FB_KPT><<<a2g, FB_BLK, 0, stream>>>(
            x, e2, E2, a2, W1_2b, b1_2b, W2_2b, b2_2b, out);
    if (a3g > 0)
        edge_mlp_atomic<6, FB_KPT><<<a3g, FB_BLK, 0, stream>>>(
            x, e3, E3, a3, W1_3b, b1_3b, W2_3b, b2_3b, out);
    if (asg > 0)
        edge_mlp_atomic<3, FB_KPT><<<asg, FB_BLK, 0, stream>>>(
            x, es, ES, as, W1_s, b1_s, W2_s, b2_s, out);
}

extern "C" void kernel_launch(void* const* d_in, const int* in_sizes, int n_in,
                              void* d_out, int out_size, void* d_ws, size_t ws_size,
                              hipStream_t stream)
{
    const float* x  = (const float*)d_in[0];
    const int*   e2 = (const int*)d_in[1];
    const int*   e3 = (const int*)d_in[2];
    const int*   es = (const int*)d_in[3];
    const float* a2 = (const float*)d_in[5];
    const float* a3 = (const float*)d_in[6];
    const float* as = (const float*)d_in[7];
    const float* W1_2b = (const float*)d_in[9];
    const float* b1_2b = (const float*)d_in[10];
    const float* W2_2b = (const float*)d_in[11];
    const float* b2_2b = (const float*)d_in[12];
    const float* W1_3b = (const float*)d_in[13];
    const float* b1_3b = (const float*)d_in[14];
    const float* W2_3b = (const float*)d_in[15];
    const float* b2_3b = (const float*)d_in[16];
    const float* W1_s  = (const float*)d_in[17];
    const float* b1_s  = (const float*)d_in[18];
    const float* W2_s  = (const float*)d_in[19];
    const float* b2_s  = (const float*)d_in[20];

    const long long E2 = in_sizes[1] / 2;
    const long long E3 = in_sizes[2] / 3;
    const long long ES = in_sizes[3] / 2;
    const long long Etot = E2 + E3 + ES;
    const int n_nodes = out_size / 3;
    const int nbuckets = (n_nodes + NPB - 1) >> NPB_SHIFT;

    float* out = (float*)d_out;

    // tiles (SPAN = 1024 = BLK*KPT)
    int g0 = (int)((E2 + 1023) / 1024);
    int g1 = (int)((ES + 1023) / 1024);
    int g2 = (int)((E3 + 1023) / 1024);
    const int T = g0 + g1 + g2;

    // ws layout: [gcount 1KB][nets][partials][x4][records]
    const size_t off_nets = 1024;
    const size_t off_part = (off_nets + 3 * NET_SLOT * 4 + 255) & ~(size_t)255;
    const size_t part_bytes = (size_t)nbuckets * PSPLIT * TILE_F * 4;
    const size_t off_x4 = (off_part + part_bytes + 255) & ~(size_t)255;
    const size_t x4_bytes = (size_t)n_nodes * sizeof(float4);
    const size_t off_rec = (off_x4 + x4_bytes + 255) & ~(size_t)255;

    long long mean_per_bucket = (Etot + nbuckets - 1) / nbuckets;
    long long min_cap = mean_per_bucket + 1600;   // ~12 sigma for binomial load
    long long cap_avail =
        ((long long)ws_size - (long long)off_rec) / ((long long)nbuckets * 16);

    bool ok = (nbuckets <= NB_MAX) && (cap_avail >= min_cap);

    if (ok) {
        long long capL = min_cap + 4096;
        if (capL > cap_avail) capL = cap_avail;

        FusedArgs args;
        args.x = x; args.n_nodes = n_nodes;
        args.e0 = e2; args.E0 = E2; args.at0 = a2;
        args.e1 = es; args.E1 = ES; args.at1 = as;
        args.e2 = e3; args.E2 = E3; args.at2 = a3;
        args.g0 = g0; args.g1 = g1; args.T = T;
        args.nbuckets = nbuckets; args.cap = (int)capL;
        args.W1_2b = W1_2b; args.b1_2b = b1_2b; args.W2_2b = W2_2b; args.b2_2b = b2_2b;
        args.W1_s = W1_s;   args.b1_s = b1_s;   args.W2_s = W2_s;   args.b2_s = b2_s;
        args.W1_3b = W1_3b; args.b1_3b = b1_3b; args.W2_3b = W2_3b; args.b2_3b = b2_3b;
        args.nets = (unsigned*)((char*)d_ws + off_nets);
        args.x4 = (float4*)((char*)d_ws + off_x4);
        args.gcount = (int*)d_ws;
        args.records = (float4*)((char*)d_ws + off_rec);
        args.partials = (float*)((char*)d_ws + off_part);
        args.out = out;

        // conservative co-residency: query occupancy, clamp to <=4 blocks/CU
        int bpc = 0;
        if (hipOccupancyMaxActiveBlocksPerMultiprocessor(
                &bpc, reinterpret_cast<const void*>(&fused_kernel), 256, 0)
                != hipSuccess || bpc < 1)
            bpc = 2;
        if (bpc > 4) bpc = 4;
        const int G = 256 * bpc;   // 256 CUs on MI355X

        void* params[] = { (void*)&args };
        hipError_t lerr = hipLaunchCooperativeKernel(
            reinterpret_cast<const void*>(&fused_kernel),
            dim3(G), dim3(256), params, 0, stream);
        if (lerr == hipSuccess) return;
        // fall through to fallback on any launch failure
    }

    launch_fallback(x,
                    e2, E2, a2, e3, E3, a3, es, ES, as,
                    W1_2b, b1_2b, W2_2b, b2_2b,
                    W1_3b, b1_3b, W2_3b, b2_3b,
                    W1_s, b1_s, W2_s, b2_s,
                    out, out_size, stream);
}